// Round 14
// baseline (212.877 us; speedup 1.0000x reference)
//
#include <hip/hip_runtime.h>
#include <stdint.h>

typedef unsigned short ushort_t;
typedef __attribute__((ext_vector_type(8))) short short8;
typedef __attribute__((ext_vector_type(4))) float floatx4;
typedef __attribute__((ext_vector_type(4))) float floatv4;
typedef __attribute__((ext_vector_type(4))) unsigned short ushortv4;

// B=64, I=128, J=512, H=16, D=64, QD=512, KVD=256, HID=1024

__device__ __forceinline__ ushort_t f2bf(float x) {
    union { float f; unsigned u; } v; v.f = x;
    unsigned r = v.u + 0x7fffu + ((v.u >> 16) & 1u);   // RNE
    return (ushort_t)(r >> 16);
}

// async global->LDS, 16B per lane; LDS dst = wave-uniform base + lane*16
__device__ __forceinline__ void gl_lds16(const ushort_t* g, ushort_t* l) {
    __builtin_amdgcn_global_load_lds(
        (const __attribute__((address_space(1))) void*)g,
        (__attribute__((address_space(3))) void*)l, 16, 0, 0);
}

// ---------------- fused prep: casts + TILED weight transposes ----------------
// casts are 8-floats/thread (2x float4 load -> one 16B bf16x8 store) [r12].
// blocks [0,2048): q cast | [2048,6144): kv cast |
// [6144,6272): Wq 64x64-tile transpose | [6272,6400): Wkv | [6400,6528): Wo
__global__ __launch_bounds__(256) void prep_kernel(
    const float* __restrict__ q, const float* __restrict__ kv,
    const float* __restrict__ Wq, const float* __restrict__ Wkv,
    const float* __restrict__ Wo,
    ushort_t* __restrict__ qA, ushort_t* __restrict__ kvA,
    ushort_t* __restrict__ WqT, ushort_t* __restrict__ WkvT,
    ushort_t* __restrict__ WoT)
{
    __shared__ ushort_t tileS[64 * 68];
    const int bid = blockIdx.x;
    const int tid = threadIdx.x;
    if (bid < 6144) {                       // q then kv: f32 -> bf16, 8/thread
        const float* src = (bid < 2048) ? q : kv;
        ushort_t* dst    = (bid < 2048) ? qA : kvA;
        size_t t = (size_t)(bid < 2048 ? bid : bid - 2048) * 256 + tid;
        const float* s = src + t * 8;
        floatv4 v0 = *(const floatv4*)s;
        floatv4 v1 = *(const floatv4*)(s + 4);
        short8 o;
        o[0] = (short)f2bf(v0[0]); o[1] = (short)f2bf(v0[1]);
        o[2] = (short)f2bf(v0[2]); o[3] = (short)f2bf(v0[3]);
        o[4] = (short)f2bf(v1[0]); o[5] = (short)f2bf(v1[1]);
        o[6] = (short)f2bf(v1[2]); o[7] = (short)f2bf(v1[3]);
        *(short8*)&dst[t * 8] = o;
        return;
    }
    // ---- 64x64 tiled transpose: dst[n*K+k] = src[k*N+n] * scale ----
    const float* src; ushort_t* dst; int K, N, kt, nt; float scale = 1.0f;
    if (bid < 6272)      { int tl = bid - 6144; src = Wq;  dst = WqT;  K = 512;  N = 1024; kt = tl >> 4; nt = tl & 15; scale = 0.125f; }
    else if (bid < 6400) { int tl = bid - 6272; src = Wkv; dst = WkvT; K = 256;  N = 2048; kt = tl >> 5; nt = tl & 31; }
    else                 { int tl = bid - 6400; src = Wo;  dst = WoT;  K = 1024; N = 512;  kt = tl >> 3; nt = tl & 7;  }
#pragma unroll
    for (int t = 0; t < 4; t++) {           // coalesced float4 reads
        int e = t * 256 + tid;
        int row = e >> 4, c4 = e & 15;
        floatv4 v = *(const floatv4*)&src[(size_t)(kt * 64 + row) * N + nt * 64 + c4 * 4];
        ushortv4 o;
        o[0] = f2bf(v[0] * scale); o[1] = f2bf(v[1] * scale);
        o[2] = f2bf(v[2] * scale); o[3] = f2bf(v[3] * scale);
        *(ushortv4*)&tileS[row * 68 + c4 * 4] = o;
    }
    __syncthreads();
#pragma unroll
    for (int t = 0; t < 4; t++) {           // coalesced 8B bf16 writes
        int e = t * 256 + tid;
        int orow = e >> 4, c4 = e & 15;
        ushortv4 o;
#pragma unroll
        for (int e2 = 0; e2 < 4; e2++) o[e2] = tileS[(c4 * 4 + e2) * 68 + orow];
        *(ushortv4*)&dst[(size_t)(nt * 64 + orow) * K + kt * 64 + c4 * 4] = o;
    }
}

// ------ GEMM: out = A (8192x1024) * Bt^T (512x1024) + bias, 64x64 tiles -----
// 1024 blocks = 4 blocks/CU (r11: verified, total -4.9us vs 128^2 tiles).
__global__ __launch_bounds__(256, 4) void gemm_bt_kernel(
    const ushort_t* __restrict__ A, const ushort_t* __restrict__ Bt,
    int M, int N, int K,
    float* __restrict__ out_f, const float* __restrict__ bias)
{
    __shared__ ushort_t smem[8192];           // sA|sB: 2 x 64x64 (16KB)
    ushort_t* sA = smem;
    ushort_t* sB = smem + 4096;

    const int bid  = blockIdx.x;              // 0..1023
    const int xcd  = bid & 7;
    const int slot = bid >> 3;                // 0..127
    const int by   = xcd * 16 + (slot & 15);  // 0..127 (M/64)
    const int bx   = slot >> 4;               // 0..7   (N/64)

    const int tid  = threadIdx.x;
    const int lane = tid & 63;
    const int w    = tid >> 6;                // 4 waves
    const int quad = lane >> 4;
    const int l15  = lane & 15;
    const int wr   = w >> 1, wc = w & 1;      // 2x2 wave grid, 32x32 each
    const int m0 = by * 64;
    const int n0 = bx * 64;

    const int rsub = lane >> 3;               // 0..7 (8 rows per gl_lds16 call)
    const int c8   = lane & 7;

    floatx4 acc[2][2];
#pragma unroll
    for (int i = 0; i < 2; i++)
#pragma unroll
        for (int j = 0; j < 2; j++) acc[i][j] = (floatx4){0.f, 0.f, 0.f, 0.f};

    for (int k0 = 0; k0 < K; k0 += 64) {
        __syncthreads();                      // prev iteration's reads done
#pragma unroll
        for (int t = 0; t < 2; t++) {         // wave w stages rows w*16..w*16+15
            int rg = w * 16 + t * 8;
            gl_lds16(&A[(size_t)(m0 + rg + rsub) * K + k0 + c8 * 8], &sA[rg * 64]);
            gl_lds16(&Bt[(size_t)(n0 + rg + rsub) * K + k0 + c8 * 8], &sB[rg * 64]);
        }
        __syncthreads();                      // staging visible (vmcnt(0) implied)
#pragma unroll
        for (int ks = 0; ks < 64; ks += 32) {
            short8 af[2], bf[2];
#pragma unroll
            for (int i = 0; i < 2; i++)
                af[i] = *(const short8*)&sA[(wr * 32 + i * 16 + l15) * 64 + ks + quad * 8];
#pragma unroll
            for (int j = 0; j < 2; j++)
                bf[j] = *(const short8*)&sB[(wc * 32 + j * 16 + l15) * 64 + ks + quad * 8];
#pragma unroll
            for (int i = 0; i < 2; i++)
#pragma unroll
                for (int j = 0; j < 2; j++)
                    acc[i][j] = __builtin_amdgcn_mfma_f32_16x16x32_bf16(
                        af[i], bf[j], acc[i][j], 0, 0, 0);
        }
    }

    // C layout: row = quad*4+r, col = lane&15 (verified m89/m91)
#pragma unroll
    for (int i = 0; i < 2; i++)
#pragma unroll
        for (int j = 0; j < 2; j++)
#pragma unroll
            for (int r = 0; r < 4; r++) {
                int grow = m0 + wr * 32 + i * 16 + quad * 4 + r;
                int gcol = n0 + wc * 32 + j * 16 + l15;
                out_f[(size_t)grow * N + gcol] = acc[i][j][r] + bias[gcol];
            }
}

// ------- fused Q-projection + KV-projection + flash attention (v18) ---------
// grid = B*H/2 = 512 blocks, 1024 threads (16 waves), 104 KB LDS -> 1 block/CU
// (same 16 waves/CU as v10's 2x8). v18 = v10's verified inner patterns with
// TWO heads per block: wave w -> head-group hg=w>>3 (h = hp*2+hg), lane-group
// wl=w&7. One kv-chunk stage + one B1/B2 pair now serve BOTH heads' proj
// (staging bytes/head and barriers/work halved; 64 proj MFMAs between
// barriers instead of 32). sQ in phase 0 is shared (same b). All fragment/
// swizzle/C-layout code is v10's with w->(hg,wl) substitution only.
__global__ __launch_bounds__(1024, 2) void fattn_kernel(
    const ushort_t* __restrict__ QA,   // qA  (b*128+i, 512) bf16
    const ushort_t* __restrict__ WQ,   // WqT (1024, 512) bf16, scale folded
    const ushort_t* __restrict__ KV,   // kvA (b*512+j, 256) bf16
    const ushort_t* __restrict__ W,    // WkvT (2048, 256) bf16
    ushort_t* __restrict__ O)          // (b*128+i, 1024)
{
    __shared__ ushort_t smem[53248];        // 106,496 B total
    ushort_t* sKV = smem;                   // main: 64x256 linear+swz (32 KB)
    ushort_t* sKc = smem + 16384;           // main: 2 x 64x72 (18.4 KB)
    ushort_t* sVt = smem + 25600;           // main: 2 x 64x72 (18.4 KB)
    ushort_t* sP  = smem + 34816;           // main: 16x16x72 (36.9 KB)
    ushort_t* sQ  = smem;                   // phase0: 128x128 linear+swz (32 KB)
    ushort_t* sW  = smem + 16384;           // phase0: 2 x 64x128 linear+swz (32 KB)

    // b-locality swizzle: xcd = bid&7 owns b in {8*xcd .. 8*xcd+7}
    const int bid  = blockIdx.x;            // 0..511
    const int xcd  = bid & 7;
    const int slot = bid >> 3;              // 0..63
    const int b  = xcd * 8 + (slot & 7);
    const int hp = slot >> 3;               // head-pair 0..7

    const int tid  = threadIdx.x;
    const int lane = tid & 63, w = tid >> 6;    // w 0..15
    const int hg   = w >> 3, wl = w & 7;        // head-group, lane-group-wave
    const int h    = hp * 2 + hg;
    const int quad = lane >> 4, l15 = lane & 15;
    const int swz  = (l15 & 7) << 3;        // read-side XOR, ushort units (16B gran)

    ushort_t* sp  = &sP[w * 1152];          // 16 x 72 per wave (private)
    ushort_t* sKc_g = &sKc[hg * 4608];      // this group's Kc (64x72)
    ushort_t* sVt_g = &sVt[hg * 4608];      // this group's Vt (64x72)

    // staging lane geometry
    const int rq = lane >> 4;               // sub-row 0..3 (4-row calls, 256B rows)
    const int gq = l15 * 8;                 // granule col, ushort units
    const int rh = lane >> 5;               // sub-row 0..1 (2-row calls, 512B rows)
    const int gk = (lane & 31) * 8;

    // ================= phase 0: q-projection for (b, h) =====================
    const ushort_t* qb = &QA[(size_t)b * 128 * 512];
    const ushort_t* wqg = &WQ[(size_t)h * 64 * 512];
    floatx4 qacc[4];
#pragma unroll
    for (int nt = 0; nt < 4; nt++) qacc[nt] = (floatx4){0.f, 0.f, 0.f, 0.f};

    for (int kc = 0; kc < 4; kc++) {
        if (kc) __syncthreads();            // prev sub-chunk reads done
#pragma unroll
        for (int t = 0; t < 2; t++) {       // sQ (shared): 8 rows/wave, 4/call
            int rb = w * 8 + t * 4;         // wave-uniform LDS row base
            int srow = rb + rq;
            int scol = kc * 128 + (gq ^ ((srow & 7) << 3));
            gl_lds16(&qb[(size_t)srow * 512 + scol], &sQ[rb * 128]);
        }
#pragma unroll
        for (int t = 0; t < 2; t++) {       // sW slice hg: 8 rows/wave, 4/call
            int rb = wl * 8 + t * 4;        // local row in 64-row slice
            int srow = rb + rq;
            int scol = kc * 128 + (gq ^ ((srow & 7) << 3));
            gl_lds16(&wqg[(size_t)srow * 512 + scol], &sW[hg * 8192 + rb * 128]);
        }
        __syncthreads();                    // staging visible (vmcnt(0) implied)
#pragma unroll
        for (int ks = 0; ks < 4; ks++) {
            short8 af = *(const short8*)&sQ[(wl * 16 + l15) * 128 + ((ks * 32 + quad * 8) ^ swz)];
#pragma unroll
            for (int nt = 0; nt < 4; nt++) {
                short8 bfr = *(const short8*)&sW[hg * 8192 + (nt * 16 + l15) * 128 + ((ks * 32 + quad * 8) ^ swz)];
                qacc[nt] = __builtin_amdgcn_mfma_f32_16x16x32_bf16(af, bfr, qacc[nt], 0, 0, 0);
            }
        }
    }
    __syncthreads();                        // all phase-0 LDS reads done

    const ushort_t* kvb = &KV[(size_t)b * 512 * 256];
    // wave w stages its rows 4w..4w+3; 2 rows (1 KB) per call.
#define STAGE_KV(CH)                                                          \
    {                                                                         \
        _Pragma("unroll")                                                     \
        for (int t = 0; t < 2; t++) {                                         \
            int rloc = 4 * w + 2 * t;       /* wave-uniform LDS row base */   \
            int srow = rloc + rh;                                             \
            int scol = gk ^ ((srow & 7) << 3);                                \
            gl_lds16(&kvb[(size_t)((CH) * 64 + srow) * 256 + scol],           \
                     &sKV[rloc * 256]);                                       \
        }                                                                     \
    }
    STAGE_KV(0);

    // qh C-frags -> per-wave sp -> A-frags (lane remap through LDS)
#pragma unroll
    for (int nt = 0; nt < 4; nt++)
#pragma unroll
        for (int r = 0; r < 4; r++)
            sp[(quad * 4 + r) * 72 + nt * 16 + l15] = f2bf(qacc[nt][r]);
    short8 aq0 = *(const short8*)&sp[l15 * 72 + quad * 8];
    short8 aq1 = *(const short8*)&sp[l15 * 72 + 32 + quad * 8];

    // ---- W (kv) fragments in registers: wave (hg,wl) owns proj n-tile wl of head h ----
    short8 wf[8];
    {
        int n = wl * 16 + l15;
        int grow = (n < 64) ? (h * 64 + n) : (1024 + h * 64 + (n - 64));
        const ushort_t* wp = &W[(size_t)grow * 256 + quad * 8];
#pragma unroll
        for (int ks = 0; ks < 8; ks++)
            wf[ks] = *(const short8*)(wp + ks * 32);
    }

    float lsum[4];
    floatx4 acc_o[4];
#pragma unroll
    for (int r = 0; r < 4; r++) lsum[r] = 0.f;
#pragma unroll
    for (int dt = 0; dt < 4; dt++) acc_o[dt] = (floatx4){0.f, 0.f, 0.f, 0.f};

    // ========================= main loop: 8 j-chunks ========================
    for (int ch = 0; ch < 8; ch++) {
        __syncthreads();                    // B1: vmcnt(0) drains prefetch; staging visible

        // ---- projection: pacc[jt] = kv_chunk(jt) @ W n-tile (h, wl), K=256 --
        // one shared sKV stage feeds BOTH head-groups' proj (64 MFMAs/wave-pair)
        floatx4 pacc[4];
#pragma unroll
        for (int jt = 0; jt < 4; jt++) pacc[jt] = (floatx4){0.f, 0.f, 0.f, 0.f};
#pragma unroll
        for (int ks = 0; ks < 8; ks++) {
            short8 af[4];
#pragma unroll
            for (int jt = 0; jt < 4; jt++)
                af[jt] = *(const short8*)&sKV[(jt * 16 + l15) * 256 + ((ks * 32 + quad * 8) ^ swz)];
#pragma unroll
            for (int jt = 0; jt < 4; jt++)
                pacc[jt] = __builtin_amdgcn_mfma_f32_16x16x32_bf16(
                    af[jt], wf[ks], pacc[jt], 0, 0, 0);
        }

        // ---- write Kc / Vc^T to group LDS (C layout: row j = quad*4+r, col = l15) --
        if (wl < 4) {
            int d = wl * 16 + l15;
#pragma unroll
            for (int jt = 0; jt < 4; jt++)
#pragma unroll
                for (int r = 0; r < 4; r++)
                    sKc_g[(jt * 16 + quad * 4 + r) * 72 + d] = f2bf(pacc[jt][r]);
        } else {
            int d = (wl - 4) * 16 + l15;
#pragma unroll
            for (int jt = 0; jt < 4; jt++) {
                ushortv4 p;
#pragma unroll
                for (int r = 0; r < 4; r++) p[r] = f2bf(pacc[jt][r]);
                *(ushortv4*)&sVt_g[d * 72 + jt * 16 + quad * 4] = p;
            }
        }
        __syncthreads();                    // B2: Kc/Vt visible; ALL proj sKV reads done

        // ---- issue next chunk's staging: hides under S+exp+PV ----
        if (ch < 7) STAGE_KV(ch + 1);

        // ---- S = Q * Kc^T (16 x 64), then P = exp(S) (no max needed) ----
#pragma unroll
        for (int jt = 0; jt < 4; jt++) {
            const ushort_t* kp = &sKc_g[(jt * 16 + l15) * 72 + quad * 8];
            short8 bk0 = *(const short8*)kp;
            short8 bk1 = *(const short8*)(kp + 32);
            floatx4 a = (floatx4){0.f, 0.f, 0.f, 0.f};
            a = __builtin_amdgcn_mfma_f32_16x16x32_bf16(aq0, bk0, a, 0, 0, 0);
            a = __builtin_amdgcn_mfma_f32_16x16x32_bf16(aq1, bk1, a, 0, 0, 0);
            ushortv4 pk;
#pragma unroll
            for (int r = 0; r < 4; r++) {
                float p = __expf(a[r]);
                lsum[r] += p;
                pk[r] = f2bf(p);
            }
#pragma unroll
            for (int r = 0; r < 4; r++)
                sp[(quad * 4 + r) * 72 + jt * 16 + l15] = pk[r];
        }

        // ---- O += P * V  (K = 64 j), per-wave private sp: no barrier ----
#pragma unroll
        for (int kk = 0; kk < 2; kk++) {
            short8 ap = *(const short8*)&sp[l15 * 72 + kk * 32 + quad * 8];
#pragma unroll
            for (int dt = 0; dt < 4; dt++) {
                short8 bv = *(const short8*)&sVt_g[(dt * 16 + l15) * 72 + kk * 32 + quad * 8];
                acc_o[dt] = __builtin_amdgcn_mfma_f32_16x16x32_bf16(ap, bv, acc_o[dt], 0, 0, 0);
            }
        }
    }

    // ---- final row-sum reduction (within 16-lane l15 groups) + write ----
#pragma unroll
    for (int r = 0; r < 4; r++) {
        float s = lsum[r];
#pragma unroll
        for (int off = 1; off < 16; off <<= 1) s += __shfl_xor(s, off);
        float inv = 1.0f / s;
        size_t rowo = (size_t)(b * 128 + wl * 16 + quad * 4 + r) * 1024 + h * 64;
#pragma unroll
        for (int dt = 0; dt < 4; dt++)
            O[rowo + dt * 16 + l15] = f2bf(acc_o[dt][r] * inv);
    }
#undef STAGE_KV
}

// ---------------- launch ----------------
extern "C" void kernel_launch(void* const* d_in, const int* in_sizes, int n_in,
                              void* d_out, int out_size, void* d_ws, size_t ws_size,
                              hipStream_t stream) {
    const float* q   = (const float*)d_in[0];   // (64,128,512)
    const float* kv  = (const float*)d_in[1];   // (64,512,256)
    const float* Wq  = (const float*)d_in[2];   // (512,1024)
    const float* Wkv = (const float*)d_in[3];   // (256,2048)
    const float* Wo  = (const float*)d_in[4];   // (1024,512)
    const float* bo  = (const float*)d_in[5];   // (512,)
    float* out = (float*)d_out;

    char* ws = (char*)d_ws;
    ushort_t* qA    = (ushort_t*)(ws + 0);          //  8 MB  (8192 x 512)
    ushort_t* kvA   = (ushort_t*)(ws + 8388608);    // 16 MB  (32768 x 256)
    ushort_t* WqT   = (ushort_t*)(ws + 25165824);   //  1 MB  (1024 x 512)
    ushort_t* WkvT  = (ushort_t*)(ws + 26214400);   //  1 MB  (2048 x 256)
    ushort_t* WoT   = (ushort_t*)(ws + 27262976);   //  1 MB  (512 x 1024)
    ushort_t* attnO = (ushort_t*)(ws + 45088768);   // 16 MB  (8192 x 1024)

    // fused prep: 8-wide casts + tiled weight transposes, one launch
    hipLaunchKernelGGL(prep_kernel, dim3(6528), dim3(256), 0, stream,
                       q, kv, Wq, Wkv, Wo, qA, kvA, WqT, WkvT, WoT);

    // fused q-proj + kv-proj + attention: 2 heads/block, shared kv staging
    hipLaunchKernelGGL(fattn_kernel, dim3(512), dim3(1024), 0, stream,
                       qA, WqT, kvA, WkvT, attnO);

    // out = attnO @ Wo + bo  -- 64x64 tiles, 1024 blocks = 4 blocks/CU
    hipLaunchKernelGGL(gemm_bt_kernel, dim3(1024), dim3(256), 0, stream,
                       attnO, WoT, 8192, 512, 1024, out, bo);
}

// Round 15
// 201.981 us; speedup vs baseline: 1.0539x; 1.0539x over previous
//
#include <hip/hip_runtime.h>
#include <stdint.h>

typedef unsigned short ushort_t;
typedef __attribute__((ext_vector_type(8))) short short8;
typedef __attribute__((ext_vector_type(4))) float floatx4;
typedef __attribute__((ext_vector_type(4))) float floatv4;
typedef __attribute__((ext_vector_type(4))) unsigned short ushortv4;

// B=64, I=128, J=512, H=16, D=64, QD=512, KVD=256, HID=1024

__device__ __forceinline__ ushort_t f2bf(float x) {
    union { float f; unsigned u; } v; v.f = x;
    unsigned r = v.u + 0x7fffu + ((v.u >> 16) & 1u);   // RNE
    return (ushort_t)(r >> 16);
}

// async global->LDS, 16B per lane; LDS dst = wave-uniform base + lane*16
__device__ __forceinline__ void gl_lds16(const ushort_t* g, ushort_t* l) {
    __builtin_amdgcn_global_load_lds(
        (const __attribute__((address_space(1))) void*)g,
        (__attribute__((address_space(3))) void*)l, 16, 0, 0);
}

// ---------------- fused prep: casts + TILED weight transposes ----------------
// casts are 8-floats/thread (2x float4 load -> one 16B bf16x8 store) [r12].
// blocks [0,2048): q cast | [2048,6144): kv cast |
// [6144,6272): Wq 64x64-tile transpose | [6272,6400): Wkv | [6400,6528): Wo
__global__ __launch_bounds__(256) void prep_kernel(
    const float* __restrict__ q, const float* __restrict__ kv,
    const float* __restrict__ Wq, const float* __restrict__ Wkv,
    const float* __restrict__ Wo,
    ushort_t* __restrict__ qA, ushort_t* __restrict__ kvA,
    ushort_t* __restrict__ WqT, ushort_t* __restrict__ WkvT,
    ushort_t* __restrict__ WoT)
{
    __shared__ ushort_t tileS[64 * 68];
    const int bid = blockIdx.x;
    const int tid = threadIdx.x;
    if (bid < 6144) {                       // q then kv: f32 -> bf16, 8/thread
        const float* src = (bid < 2048) ? q : kv;
        ushort_t* dst    = (bid < 2048) ? qA : kvA;
        size_t t = (size_t)(bid < 2048 ? bid : bid - 2048) * 256 + tid;
        const float* s = src + t * 8;
        floatv4 v0 = *(const floatv4*)s;
        floatv4 v1 = *(const floatv4*)(s + 4);
        short8 o;
        o[0] = (short)f2bf(v0[0]); o[1] = (short)f2bf(v0[1]);
        o[2] = (short)f2bf(v0[2]); o[3] = (short)f2bf(v0[3]);
        o[4] = (short)f2bf(v1[0]); o[5] = (short)f2bf(v1[1]);
        o[6] = (short)f2bf(v1[2]); o[7] = (short)f2bf(v1[3]);
        *(short8*)&dst[t * 8] = o;
        return;
    }
    // ---- 64x64 tiled transpose: dst[n*K+k] = src[k*N+n] * scale ----
    const float* src; ushort_t* dst; int K, N, kt, nt; float scale = 1.0f;
    if (bid < 6272)      { int tl = bid - 6144; src = Wq;  dst = WqT;  K = 512;  N = 1024; kt = tl >> 4; nt = tl & 15; scale = 0.125f; }
    else if (bid < 6400) { int tl = bid - 6272; src = Wkv; dst = WkvT; K = 256;  N = 2048; kt = tl >> 5; nt = tl & 31; }
    else                 { int tl = bid - 6400; src = Wo;  dst = WoT;  K = 1024; N = 512;  kt = tl >> 3; nt = tl & 7;  }
#pragma unroll
    for (int t = 0; t < 4; t++) {           // coalesced float4 reads
        int e = t * 256 + tid;
        int row = e >> 4, c4 = e & 15;
        floatv4 v = *(const floatv4*)&src[(size_t)(kt * 64 + row) * N + nt * 64 + c4 * 4];
        ushortv4 o;
        o[0] = f2bf(v[0] * scale); o[1] = f2bf(v[1] * scale);
        o[2] = f2bf(v[2] * scale); o[3] = f2bf(v[3] * scale);
        *(ushortv4*)&tileS[row * 68 + c4 * 4] = o;
    }
    __syncthreads();
#pragma unroll
    for (int t = 0; t < 4; t++) {           // coalesced 8B bf16 writes
        int e = t * 256 + tid;
        int orow = e >> 4, c4 = e & 15;
        ushortv4 o;
#pragma unroll
        for (int e2 = 0; e2 < 4; e2++) o[e2] = tileS[(c4 * 4 + e2) * 68 + orow];
        *(ushortv4*)&dst[(size_t)(nt * 64 + orow) * K + kt * 64 + c4 * 4] = o;
    }
}

// ------ GEMM: out = A (8192x1024) * Bt^T (512x1024) + bias, 64x64 tiles -----
// 1024 blocks = 4 blocks/CU (r11: verified, total -4.9us vs 128^2 tiles).
__global__ __launch_bounds__(256, 4) void gemm_bt_kernel(
    const ushort_t* __restrict__ A, const ushort_t* __restrict__ Bt,
    int M, int N, int K,
    float* __restrict__ out_f, const float* __restrict__ bias)
{
    __shared__ ushort_t smem[8192];           // sA|sB: 2 x 64x64 (16KB)
    ushort_t* sA = smem;
    ushort_t* sB = smem + 4096;

    const int bid  = blockIdx.x;              // 0..1023
    const int xcd  = bid & 7;
    const int slot = bid >> 3;                // 0..127
    const int by   = xcd * 16 + (slot & 15);  // 0..127 (M/64)
    const int bx   = slot >> 4;               // 0..7   (N/64)

    const int tid  = threadIdx.x;
    const int lane = tid & 63;
    const int w    = tid >> 6;                // 4 waves
    const int quad = lane >> 4;
    const int l15  = lane & 15;
    const int wr   = w >> 1, wc = w & 1;      // 2x2 wave grid, 32x32 each
    const int m0 = by * 64;
    const int n0 = bx * 64;

    const int rsub = lane >> 3;               // 0..7 (8 rows per gl_lds16 call)
    const int c8   = lane & 7;

    floatx4 acc[2][2];
#pragma unroll
    for (int i = 0; i < 2; i++)
#pragma unroll
        for (int j = 0; j < 2; j++) acc[i][j] = (floatx4){0.f, 0.f, 0.f, 0.f};

    for (int k0 = 0; k0 < K; k0 += 64) {
        __syncthreads();                      // prev iteration's reads done
#pragma unroll
        for (int t = 0; t < 2; t++) {         // wave w stages rows w*16..w*16+15
            int rg = w * 16 + t * 8;
            gl_lds16(&A[(size_t)(m0 + rg + rsub) * K + k0 + c8 * 8], &sA[rg * 64]);
            gl_lds16(&Bt[(size_t)(n0 + rg + rsub) * K + k0 + c8 * 8], &sB[rg * 64]);
        }
        __syncthreads();                      // staging visible (vmcnt(0) implied)
#pragma unroll
        for (int ks = 0; ks < 64; ks += 32) {
            short8 af[2], bf[2];
#pragma unroll
            for (int i = 0; i < 2; i++)
                af[i] = *(const short8*)&sA[(wr * 32 + i * 16 + l15) * 64 + ks + quad * 8];
#pragma unroll
            for (int j = 0; j < 2; j++)
                bf[j] = *(const short8*)&sB[(wc * 32 + j * 16 + l15) * 64 + ks + quad * 8];
#pragma unroll
            for (int i = 0; i < 2; i++)
#pragma unroll
                for (int j = 0; j < 2; j++)
                    acc[i][j] = __builtin_amdgcn_mfma_f32_16x16x32_bf16(
                        af[i], bf[j], acc[i][j], 0, 0, 0);
        }
    }

    // C layout: row = quad*4+r, col = lane&15 (verified m89/m91)
#pragma unroll
    for (int i = 0; i < 2; i++)
#pragma unroll
        for (int j = 0; j < 2; j++)
#pragma unroll
            for (int r = 0; r < 4; r++) {
                int grow = m0 + wr * 32 + i * 16 + quad * 4 + r;
                int gcol = n0 + wc * 32 + j * 16 + l15;
                out_f[(size_t)grow * N + gcol] = acc[i][j][r] + bias[gcol];
            }
}

// ------- fused Q-projection + KV-projection + flash attention (v10) ---------
// grid = B*H = 1024 blocks, 512 threads (8 waves), 69.6 KB LDS -> 2 blocks/CU.
// VERBATIM the verified 97.9us kernel -- the structure's measured optimum.
// 14-round ledger: occupancy +3%, async-stage +3%, prefetch 0, conflicts at
// b128 floor, proj retile -15%, setprio -2%, global-direct phase0 failed x2,
// 2-heads/block -8%. The v10 balance of {2 blocks/CU co-residency, 8-wave
// barriers, gl_lds staging issued under S+PV} is the operating point.
__global__ __launch_bounds__(512, 4) void fattn_kernel(
    const ushort_t* __restrict__ QA,   // qA  (b*128+i, 512) bf16
    const ushort_t* __restrict__ WQ,   // WqT (1024, 512) bf16, scale folded
    const ushort_t* __restrict__ KV,   // kvA (b*512+j, 256) bf16
    const ushort_t* __restrict__ W,    // WkvT (2048, 256) bf16
    ushort_t* __restrict__ O)          // (b*128+i, 1024)
{
    __shared__ ushort_t smem[34816];        // 69,632 B total
    ushort_t* sKV = smem;                   // main: 64x256 linear+swz (32 KB)
    ushort_t* sKc = smem + 16384;           // main: 64x72   ( 9.2 KB)
    ushort_t* sVt = smem + 20992;           // main: 64x72   ( 9.2 KB)
    ushort_t* sP  = smem + 25600;           // main: 8x16x72 (18.4 KB)
    ushort_t* sQ  = smem;                   // phase0: 128x128 linear+swz (32 KB)
    ushort_t* sW  = smem + 16384;           // phase0: 64x128 linear+swz (16 KB)

    // b-locality swizzle: xcd = bid&7 owns b in {8*xcd .. 8*xcd+7}
    const int bid  = blockIdx.x;
    const int xcd  = bid & 7;
    const int slot = bid >> 3;              // 0..127
    const int b = xcd * 8 + (slot & 7);
    const int h = slot >> 3;

    const int tid  = threadIdx.x;
    const int lane = tid & 63, w = tid >> 6;
    const int quad = lane >> 4, l15 = lane & 15;
    const int swz  = (l15 & 7) << 3;        // read-side XOR, ushort units (16B gran)

    ushort_t* sp = &sP[w * 1152];           // 16 x 72 per wave (private)

    // staging lane geometry
    const int rq = lane >> 4;               // sub-row 0..3 (4-row calls, 256B rows)
    const int gq = l15 * 8;                 // granule col, ushort units
    const int rh = lane >> 5;               // sub-row 0..1 (2-row calls, 512B rows)
    const int gk = (lane & 31) * 8;

    // ================= phase 0: q-projection for this (b,h) =================
    const ushort_t* qb = &QA[(size_t)b * 128 * 512];
    const ushort_t* wq = &WQ[(size_t)h * 64 * 512];
    floatx4 qacc[4];
#pragma unroll
    for (int nt = 0; nt < 4; nt++) qacc[nt] = (floatx4){0.f, 0.f, 0.f, 0.f};

    for (int kc = 0; kc < 4; kc++) {
        if (kc) __syncthreads();            // prev sub-chunk reads done
#pragma unroll
        for (int t = 0; t < 4; t++) {       // sQ: 16 rows/wave, 4 rows/call
            int rb = w * 16 + t * 4;        // wave-uniform LDS row base
            int srow = rb + rq;
            int scol = kc * 128 + (gq ^ ((srow & 7) << 3));
            gl_lds16(&qb[(size_t)srow * 512 + scol], &sQ[rb * 128]);
        }
#pragma unroll
        for (int t = 0; t < 2; t++) {       // sW: 8 rows/wave, 4 rows/call
            int rb = w * 8 + t * 4;
            int srow = rb + rq;
            int scol = kc * 128 + (gq ^ ((srow & 7) << 3));
            gl_lds16(&wq[(size_t)srow * 512 + scol], &sW[rb * 128]);
        }
        __syncthreads();                    // staging visible (vmcnt(0) implied)
#pragma unroll
        for (int ks = 0; ks < 4; ks++) {
            short8 af = *(const short8*)&sQ[(w * 16 + l15) * 128 + ((ks * 32 + quad * 8) ^ swz)];
#pragma unroll
            for (int nt = 0; nt < 4; nt++) {
                short8 bfr = *(const short8*)&sW[(nt * 16 + l15) * 128 + ((ks * 32 + quad * 8) ^ swz)];
                qacc[nt] = __builtin_amdgcn_mfma_f32_16x16x32_bf16(af, bfr, qacc[nt], 0, 0, 0);
            }
        }
    }
    __syncthreads();                        // all phase-0 LDS reads done

    const ushort_t* kvb = &KV[(size_t)b * 512 * 256];
    // issue kv chunk-0 staging NOW: covered by qh remap + wf loads below.
    // wave w stages its rows 8w..8w+7; 2 rows (1 KB) per call.
#define STAGE_KV(CH)                                                          \
    {                                                                         \
        _Pragma("unroll")                                                     \
        for (int t = 0; t < 4; t++) {                                         \
            int rloc = 8 * w + 2 * t;       /* wave-uniform LDS row base */   \
            int srow = rloc + rh;                                             \
            int scol = gk ^ ((srow & 7) << 3);                                \
            gl_lds16(&kvb[(size_t)((CH) * 64 + srow) * 256 + scol],           \
                     &sKV[rloc * 256]);                                       \
        }                                                                     \
    }
    STAGE_KV(0);

    // qh C-frags -> per-wave sp -> A-frags (lane remap through LDS)
#pragma unroll
    for (int nt = 0; nt < 4; nt++)
#pragma unroll
        for (int r = 0; r < 4; r++)
            sp[(quad * 4 + r) * 72 + nt * 16 + l15] = f2bf(qacc[nt][r]);
    short8 aq0 = *(const short8*)&sp[l15 * 72 + quad * 8];
    short8 aq1 = *(const short8*)&sp[l15 * 72 + 32 + quad * 8];

    // ---- W (kv) fragments in registers: wave w owns proj n-tile w ----
    short8 wf[8];
    {
        int n = w * 16 + l15;
        int grow = (n < 64) ? (h * 64 + n) : (1024 + h * 64 + (n - 64));
        const ushort_t* wp = &W[(size_t)grow * 256 + quad * 8];
#pragma unroll
        for (int ks = 0; ks < 8; ks++)
            wf[ks] = *(const short8*)(wp + ks * 32);
    }

    float lsum[4];
    floatx4 acc_o[4];
#pragma unroll
    for (int r = 0; r < 4; r++) lsum[r] = 0.f;
#pragma unroll
    for (int dt = 0; dt < 4; dt++) acc_o[dt] = (floatx4){0.f, 0.f, 0.f, 0.f};

    // ========================= main loop: 8 j-chunks ========================
    for (int ch = 0; ch < 8; ch++) {
        __syncthreads();                    // B1: vmcnt(0) drains prefetch; staging visible

        // ---- projection: pacc[jt] = kv_chunk(jt) @ W n-tile w, K=256 ----
        floatx4 pacc[4];
#pragma unroll
        for (int jt = 0; jt < 4; jt++) pacc[jt] = (floatx4){0.f, 0.f, 0.f, 0.f};
#pragma unroll
        for (int ks = 0; ks < 8; ks++) {
            short8 af[4];
#pragma unroll
            for (int jt = 0; jt < 4; jt++)
                af[jt] = *(const short8*)&sKV[(jt * 16 + l15) * 256 + ((ks * 32 + quad * 8) ^ swz)];
#pragma unroll
            for (int jt = 0; jt < 4; jt++)
                pacc[jt] = __builtin_amdgcn_mfma_f32_16x16x32_bf16(
                    af[jt], wf[ks], pacc[jt], 0, 0, 0);
        }

        // ---- write Kc / Vc^T to LDS (C layout: row j = quad*4+r, col = l15) --
        if (w < 4) {
            int d = w * 16 + l15;
#pragma unroll
            for (int jt = 0; jt < 4; jt++)
#pragma unroll
                for (int r = 0; r < 4; r++)
                    sKc[(jt * 16 + quad * 4 + r) * 72 + d] = f2bf(pacc[jt][r]);
        } else {
            int d = (w - 4) * 16 + l15;
#pragma unroll
            for (int jt = 0; jt < 4; jt++) {
                ushortv4 p;
#pragma unroll
                for (int r = 0; r < 4; r++) p[r] = f2bf(pacc[jt][r]);
                *(ushortv4*)&sVt[d * 72 + jt * 16 + quad * 4] = p;
            }
        }
        __syncthreads();                    // B2: Kc/Vt visible; ALL proj sKV reads done

        // ---- issue next chunk's staging: hides under S+exp+PV ----
        if (ch < 7) STAGE_KV(ch + 1);

        // ---- S = Q * Kc^T (16 x 64), then P = exp(S) (no max needed) ----
#pragma unroll
        for (int jt = 0; jt < 4; jt++) {
            const ushort_t* kp = &sKc[(jt * 16 + l15) * 72 + quad * 8];
            short8 bk0 = *(const short8*)kp;
            short8 bk1 = *(const short8*)(kp + 32);
            floatx4 a = (floatx4){0.f, 0.f, 0.f, 0.f};
            a = __builtin_amdgcn_mfma_f32_16x16x32_bf16(aq0, bk0, a, 0, 0, 0);
            a = __builtin_amdgcn_mfma_f32_16x16x32_bf16(aq1, bk1, a, 0, 0, 0);
            ushortv4 pk;
#pragma unroll
            for (int r = 0; r < 4; r++) {
                float p = __expf(a[r]);
                lsum[r] += p;
                pk[r] = f2bf(p);
            }
#pragma unroll
            for (int r = 0; r < 4; r++)
                sp[(quad * 4 + r) * 72 + jt * 16 + l15] = pk[r];
        }

        // ---- O += P * V  (K = 64 j), per-wave private sp: no barrier ----
#pragma unroll
        for (int kk = 0; kk < 2; kk++) {
            short8 ap = *(const short8*)&sp[l15 * 72 + kk * 32 + quad * 8];
#pragma unroll
            for (int dt = 0; dt < 4; dt++) {
                short8 bv = *(const short8*)&sVt[(dt * 16 + l15) * 72 + kk * 32 + quad * 8];
                acc_o[dt] = __builtin_amdgcn_mfma_f32_16x16x32_bf16(ap, bv, acc_o[dt], 0, 0, 0);
            }
        }
    }

    // ---- final row-sum reduction (within 16-lane l15 groups) + write ----
#pragma unroll
    for (int r = 0; r < 4; r++) {
        float s = lsum[r];
#pragma unroll
        for (int off = 1; off < 16; off <<= 1) s += __shfl_xor(s, off);
        float inv = 1.0f / s;
        size_t rowo = (size_t)(b * 128 + w * 16 + quad * 4 + r) * 1024 + h * 64;
#pragma unroll
        for (int dt = 0; dt < 4; dt++)
            O[rowo + dt * 16 + l15] = f2bf(acc_o[dt][r] * inv);
    }
#undef STAGE_KV
}

// ---------------- launch ----------------
extern "C" void kernel_launch(void* const* d_in, const int* in_sizes, int n_in,
                              void* d_out, int out_size, void* d_ws, size_t ws_size,
                              hipStream_t stream) {
    const float* q   = (const float*)d_in[0];   // (64,128,512)
    const float* kv  = (const float*)d_in[1];   // (64,512,256)
    const float* Wq  = (const float*)d_in[2];   // (512,1024)
    const float* Wkv = (const float*)d_in[3];   // (256,2048)
    const float* Wo  = (const float*)d_in[4];   // (1024,512)
    const float* bo  = (const float*)d_in[5];   // (512,)
    float* out = (float*)d_out;

    char* ws = (char*)d_ws;
    ushort_t* qA    = (ushort_t*)(ws + 0);          //  8 MB  (8192 x 512)
    ushort_t* kvA   = (ushort_t*)(ws + 8388608);    // 16 MB  (32768 x 256)
    ushort_t* WqT   = (ushort_t*)(ws + 25165824);   //  1 MB  (1024 x 512)
    ushort_t* WkvT  = (ushort_t*)(ws + 26214400);   //  1 MB  (2048 x 256)
    ushort_t* WoT   = (ushort_t*)(ws + 27262976);   //  1 MB  (512 x 1024)
    ushort_t* attnO = (ushort_t*)(ws + 45088768);   // 16 MB  (8192 x 1024)

    // fused prep: 8-wide casts + tiled weight transposes, one launch
    hipLaunchKernelGGL(prep_kernel, dim3(6528), dim3(256), 0, stream,
                       q, kv, Wq, Wkv, Wo, qA, kvA, WqT, WkvT, WoT);

    // fused q-proj + kv-proj + attention (v10 verbatim, verified 97.9 us)
    hipLaunchKernelGGL(fattn_kernel, dim3(1024), dim3(512), 0, stream,
                       qA, WqT, kvA, WkvT, attnO);

    // out = attnO @ Wo + bo  -- 64x64 tiles, 1024 blocks = 4 blocks/CU
    hipLaunchKernelGGL(gemm_bt_kernel, dim3(1024), dim3(256), 0, stream,
                       attnO, WoT, 8192, 512, 1024, out, bo);
}

// Round 16
// 200.736 us; speedup vs baseline: 1.0605x; 1.0062x over previous
//
#include <hip/hip_runtime.h>
#include <hip/hip_bf16.h>
#include <stdint.h>

typedef unsigned short ushort_t;
typedef __attribute__((ext_vector_type(8))) short short8;
typedef __attribute__((ext_vector_type(4))) float floatx4;
typedef __attribute__((ext_vector_type(4))) float floatv4;
typedef __attribute__((ext_vector_type(4))) unsigned short ushortv4;

// B=64, I=128, J=512, H=16, D=64, QD=512, KVD=256, HID=1024

// v19: NATIVE bf16 cast (RNE) instead of manual bit-twiddle. The compiler
// fuses adjacent casts into v_cvt_pk_bf16_f32 (2 f32 -> 1 VALU op); the
// manual union+add+shift form (~3-4 ops each) cannot be pattern-matched
// (m240: compiler handles packed cvt for scalar casts; hand-rolled loses).
__device__ __forceinline__ ushort_t f2bf(float x) {
    union { __hip_bfloat16 b; ushort_t u; } v;
    v.b = __float2bfloat16(x);
    return v.u;
}

// async global->LDS, 16B per lane; LDS dst = wave-uniform base + lane*16
__device__ __forceinline__ void gl_lds16(const ushort_t* g, ushort_t* l) {
    __builtin_amdgcn_global_load_lds(
        (const __attribute__((address_space(1))) void*)g,
        (__attribute__((address_space(3))) void*)l, 16, 0, 0);
}

// ---------------- fused prep: casts + TILED weight transposes ----------------
// casts are 8-floats/thread (2x float4 load -> one 16B bf16x8 store) [r12].
// blocks [0,2048): q cast | [2048,6144): kv cast |
// [6144,6272): Wq 64x64-tile transpose | [6272,6400): Wkv | [6400,6528): Wo
__global__ __launch_bounds__(256) void prep_kernel(
    const float* __restrict__ q, const float* __restrict__ kv,
    const float* __restrict__ Wq, const float* __restrict__ Wkv,
    const float* __restrict__ Wo,
    ushort_t* __restrict__ qA, ushort_t* __restrict__ kvA,
    ushort_t* __restrict__ WqT, ushort_t* __restrict__ WkvT,
    ushort_t* __restrict__ WoT)
{
    __shared__ ushort_t tileS[64 * 68];
    const int bid = blockIdx.x;
    const int tid = threadIdx.x;
    if (bid < 6144) {                       // q then kv: f32 -> bf16, 8/thread
        const float* src = (bid < 2048) ? q : kv;
        ushort_t* dst    = (bid < 2048) ? qA : kvA;
        size_t t = (size_t)(bid < 2048 ? bid : bid - 2048) * 256 + tid;
        const float* s = src + t * 8;
        floatv4 v0 = *(const floatv4*)s;
        floatv4 v1 = *(const floatv4*)(s + 4);
        short8 o;
        o[0] = (short)f2bf(v0[0]); o[1] = (short)f2bf(v0[1]);
        o[2] = (short)f2bf(v0[2]); o[3] = (short)f2bf(v0[3]);
        o[4] = (short)f2bf(v1[0]); o[5] = (short)f2bf(v1[1]);
        o[6] = (short)f2bf(v1[2]); o[7] = (short)f2bf(v1[3]);
        *(short8*)&dst[t * 8] = o;
        return;
    }
    // ---- 64x64 tiled transpose: dst[n*K+k] = src[k*N+n] * scale ----
    const float* src; ushort_t* dst; int K, N, kt, nt; float scale = 1.0f;
    if (bid < 6272)      { int tl = bid - 6144; src = Wq;  dst = WqT;  K = 512;  N = 1024; kt = tl >> 4; nt = tl & 15; scale = 0.125f; }
    else if (bid < 6400) { int tl = bid - 6272; src = Wkv; dst = WkvT; K = 256;  N = 2048; kt = tl >> 5; nt = tl & 31; }
    else                 { int tl = bid - 6400; src = Wo;  dst = WoT;  K = 1024; N = 512;  kt = tl >> 3; nt = tl & 7;  }
#pragma unroll
    for (int t = 0; t < 4; t++) {           // coalesced float4 reads
        int e = t * 256 + tid;
        int row = e >> 4, c4 = e & 15;
        floatv4 v = *(const floatv4*)&src[(size_t)(kt * 64 + row) * N + nt * 64 + c4 * 4];
        ushortv4 o;
        o[0] = f2bf(v[0] * scale); o[1] = f2bf(v[1] * scale);
        o[2] = f2bf(v[2] * scale); o[3] = f2bf(v[3] * scale);
        *(ushortv4*)&tileS[row * 68 + c4 * 4] = o;
    }
    __syncthreads();
#pragma unroll
    for (int t = 0; t < 4; t++) {           // coalesced 8B bf16 writes
        int e = t * 256 + tid;
        int orow = e >> 4, c4 = e & 15;
        ushortv4 o;
#pragma unroll
        for (int e2 = 0; e2 < 4; e2++) o[e2] = tileS[(c4 * 4 + e2) * 68 + orow];
        *(ushortv4*)&dst[(size_t)(nt * 64 + orow) * K + kt * 64 + c4 * 4] = o;
    }
}

// ------ GEMM: out = A (8192x1024) * Bt^T (512x1024) + bias, 64x64 tiles -----
// 1024 blocks = 4 blocks/CU (r11: verified, total -4.9us vs 128^2 tiles).
__global__ __launch_bounds__(256, 4) void gemm_bt_kernel(
    const ushort_t* __restrict__ A, const ushort_t* __restrict__ Bt,
    int M, int N, int K,
    float* __restrict__ out_f, const float* __restrict__ bias)
{
    __shared__ ushort_t smem[8192];           // sA|sB: 2 x 64x64 (16KB)
    ushort_t* sA = smem;
    ushort_t* sB = smem + 4096;

    const int bid  = blockIdx.x;              // 0..1023
    const int xcd  = bid & 7;
    const int slot = bid >> 3;                // 0..127
    const int by   = xcd * 16 + (slot & 15);  // 0..127 (M/64)
    const int bx   = slot >> 4;               // 0..7   (N/64)

    const int tid  = threadIdx.x;
    const int lane = tid & 63;
    const int w    = tid >> 6;                // 4 waves
    const int quad = lane >> 4;
    const int l15  = lane & 15;
    const int wr   = w >> 1, wc = w & 1;      // 2x2 wave grid, 32x32 each
    const int m0 = by * 64;
    const int n0 = bx * 64;

    const int rsub = lane >> 3;               // 0..7 (8 rows per gl_lds16 call)
    const int c8   = lane & 7;

    floatx4 acc[2][2];
#pragma unroll
    for (int i = 0; i < 2; i++)
#pragma unroll
        for (int j = 0; j < 2; j++) acc[i][j] = (floatx4){0.f, 0.f, 0.f, 0.f};

    for (int k0 = 0; k0 < K; k0 += 64) {
        __syncthreads();                      // prev iteration's reads done
#pragma unroll
        for (int t = 0; t < 2; t++) {         // wave w stages rows w*16..w*16+15
            int rg = w * 16 + t * 8;
            gl_lds16(&A[(size_t)(m0 + rg + rsub) * K + k0 + c8 * 8], &sA[rg * 64]);
            gl_lds16(&Bt[(size_t)(n0 + rg + rsub) * K + k0 + c8 * 8], &sB[rg * 64]);
        }
        __syncthreads();                      // staging visible (vmcnt(0) implied)
#pragma unroll
        for (int ks = 0; ks < 64; ks += 32) {
            short8 af[2], bf[2];
#pragma unroll
            for (int i = 0; i < 2; i++)
                af[i] = *(const short8*)&sA[(wr * 32 + i * 16 + l15) * 64 + ks + quad * 8];
#pragma unroll
            for (int j = 0; j < 2; j++)
                bf[j] = *(const short8*)&sB[(wc * 32 + j * 16 + l15) * 64 + ks + quad * 8];
#pragma unroll
            for (int i = 0; i < 2; i++)
#pragma unroll
                for (int j = 0; j < 2; j++)
                    acc[i][j] = __builtin_amdgcn_mfma_f32_16x16x32_bf16(
                        af[i], bf[j], acc[i][j], 0, 0, 0);
        }
    }

    // C layout: row = quad*4+r, col = lane&15 (verified m89/m91)
#pragma unroll
    for (int i = 0; i < 2; i++)
#pragma unroll
        for (int j = 0; j < 2; j++)
#pragma unroll
            for (int r = 0; r < 4; r++) {
                int grow = m0 + wr * 32 + i * 16 + quad * 4 + r;
                int gcol = n0 + wc * 32 + j * 16 + l15;
                out_f[(size_t)grow * N + gcol] = acc[i][j][r] + bias[gcol];
            }
}

// ------- fused Q-projection + KV-projection + flash attention (v19) ---------
// grid = B*H = 1024 blocks, 512 threads (8 waves), 69.6 KB LDS -> 2 blocks/CU.
// v19 = v10 structure (verified operating point) + native-cast f2bf so the
// compiler emits packed v_cvt_pk_bf16_f32 in the Kc/Vt-write, P-write,
// qacc-remap and O-write loops (32 conversions/wave/chunk were ~100+ VALU
// instrs with the manual form -- comparable to the chunk's MFMA time).
// 15-round ledger: occupancy +3%, async-stage +3%, prefetch 0, conflicts at
// b128 floor, proj retile -15%, setprio -2%, global-direct phase0 failed x2,
// 2-heads/block -8%. All other structure frozen.
__global__ __launch_bounds__(512, 4) void fattn_kernel(
    const ushort_t* __restrict__ QA,   // qA  (b*128+i, 512) bf16
    const ushort_t* __restrict__ WQ,   // WqT (1024, 512) bf16, scale folded
    const ushort_t* __restrict__ KV,   // kvA (b*512+j, 256) bf16
    const ushort_t* __restrict__ W,    // WkvT (2048, 256) bf16
    ushort_t* __restrict__ O)          // (b*128+i, 1024)
{
    __shared__ ushort_t smem[34816];        // 69,632 B total
    ushort_t* sKV = smem;                   // main: 64x256 linear+swz (32 KB)
    ushort_t* sKc = smem + 16384;           // main: 64x72   ( 9.2 KB)
    ushort_t* sVt = smem + 20992;           // main: 64x72   ( 9.2 KB)
    ushort_t* sP  = smem + 25600;           // main: 8x16x72 (18.4 KB)
    ushort_t* sQ  = smem;                   // phase0: 128x128 linear+swz (32 KB)
    ushort_t* sW  = smem + 16384;           // phase0: 64x128 linear+swz (16 KB)

    // b-locality swizzle: xcd = bid&7 owns b in {8*xcd .. 8*xcd+7}
    const int bid  = blockIdx.x;
    const int xcd  = bid & 7;
    const int slot = bid >> 3;              // 0..127
    const int b = xcd * 8 + (slot & 7);
    const int h = slot >> 3;

    const int tid  = threadIdx.x;
    const int lane = tid & 63, w = tid >> 6;
    const int quad = lane >> 4, l15 = lane & 15;
    const int swz  = (l15 & 7) << 3;        // read-side XOR, ushort units (16B gran)

    ushort_t* sp = &sP[w * 1152];           // 16 x 72 per wave (private)

    // staging lane geometry
    const int rq = lane >> 4;               // sub-row 0..3 (4-row calls, 256B rows)
    const int gq = l15 * 8;                 // granule col, ushort units
    const int rh = lane >> 5;               // sub-row 0..1 (2-row calls, 512B rows)
    const int gk = (lane & 31) * 8;

    // ================= phase 0: q-projection for this (b,h) =================
    const ushort_t* qb = &QA[(size_t)b * 128 * 512];
    const ushort_t* wq = &WQ[(size_t)h * 64 * 512];
    floatx4 qacc[4];
#pragma unroll
    for (int nt = 0; nt < 4; nt++) qacc[nt] = (floatx4){0.f, 0.f, 0.f, 0.f};

    for (int kc = 0; kc < 4; kc++) {
        if (kc) __syncthreads();            // prev sub-chunk reads done
#pragma unroll
        for (int t = 0; t < 4; t++) {       // sQ: 16 rows/wave, 4 rows/call
            int rb = w * 16 + t * 4;        // wave-uniform LDS row base
            int srow = rb + rq;
            int scol = kc * 128 + (gq ^ ((srow & 7) << 3));
            gl_lds16(&qb[(size_t)srow * 512 + scol], &sQ[rb * 128]);
        }
#pragma unroll
        for (int t = 0; t < 2; t++) {       // sW: 8 rows/wave, 4 rows/call
            int rb = w * 8 + t * 4;
            int srow = rb + rq;
            int scol = kc * 128 + (gq ^ ((srow & 7) << 3));
            gl_lds16(&wq[(size_t)srow * 512 + scol], &sW[rb * 128]);
        }
        __syncthreads();                    // staging visible (vmcnt(0) implied)
#pragma unroll
        for (int ks = 0; ks < 4; ks++) {
            short8 af = *(const short8*)&sQ[(w * 16 + l15) * 128 + ((ks * 32 + quad * 8) ^ swz)];
#pragma unroll
            for (int nt = 0; nt < 4; nt++) {
                short8 bfr = *(const short8*)&sW[(nt * 16 + l15) * 128 + ((ks * 32 + quad * 8) ^ swz)];
                qacc[nt] = __builtin_amdgcn_mfma_f32_16x16x32_bf16(af, bfr, qacc[nt], 0, 0, 0);
            }
        }
    }
    __syncthreads();                        // all phase-0 LDS reads done

    const ushort_t* kvb = &KV[(size_t)b * 512 * 256];
    // issue kv chunk-0 staging NOW: covered by qh remap + wf loads below.
    // wave w stages its rows 8w..8w+7; 2 rows (1 KB) per call.
#define STAGE_KV(CH)                                                          \
    {                                                                         \
        _Pragma("unroll")                                                     \
        for (int t = 0; t < 4; t++) {                                         \
            int rloc = 8 * w + 2 * t;       /* wave-uniform LDS row base */   \
            int srow = rloc + rh;                                             \
            int scol = gk ^ ((srow & 7) << 3);                                \
            gl_lds16(&kvb[(size_t)((CH) * 64 + srow) * 256 + scol],           \
                     &sKV[rloc * 256]);                                       \
        }                                                                     \
    }
    STAGE_KV(0);

    // qh C-frags -> per-wave sp -> A-frags (lane remap through LDS)
#pragma unroll
    for (int nt = 0; nt < 4; nt++)
#pragma unroll
        for (int r = 0; r < 4; r++)
            sp[(quad * 4 + r) * 72 + nt * 16 + l15] = f2bf(qacc[nt][r]);
    short8 aq0 = *(const short8*)&sp[l15 * 72 + quad * 8];
    short8 aq1 = *(const short8*)&sp[l15 * 72 + 32 + quad * 8];

    // ---- W (kv) fragments in registers: wave w owns proj n-tile w ----
    short8 wf[8];
    {
        int n = w * 16 + l15;
        int grow = (n < 64) ? (h * 64 + n) : (1024 + h * 64 + (n - 64));
        const ushort_t* wp = &W[(size_t)grow * 256 + quad * 8];
#pragma unroll
        for (int ks = 0; ks < 8; ks++)
            wf[ks] = *(const short8*)(wp + ks * 32);
    }

    float lsum[4];
    floatx4 acc_o[4];
#pragma unroll
    for (int r = 0; r < 4; r++) lsum[r] = 0.f;
#pragma unroll
    for (int dt = 0; dt < 4; dt++) acc_o[dt] = (floatx4){0.f, 0.f, 0.f, 0.f};

    // ========================= main loop: 8 j-chunks ========================
    for (int ch = 0; ch < 8; ch++) {
        __syncthreads();                    // B1: vmcnt(0) drains prefetch; staging visible

        // ---- projection: pacc[jt] = kv_chunk(jt) @ W n-tile w, K=256 ----
        floatx4 pacc[4];
#pragma unroll
        for (int jt = 0; jt < 4; jt++) pacc[jt] = (floatx4){0.f, 0.f, 0.f, 0.f};
#pragma unroll
        for (int ks = 0; ks < 8; ks++) {
            short8 af[4];
#pragma unroll
            for (int jt = 0; jt < 4; jt++)
                af[jt] = *(const short8*)&sKV[(jt * 16 + l15) * 256 + ((ks * 32 + quad * 8) ^ swz)];
#pragma unroll
            for (int jt = 0; jt < 4; jt++)
                pacc[jt] = __builtin_amdgcn_mfma_f32_16x16x32_bf16(
                    af[jt], wf[ks], pacc[jt], 0, 0, 0);
        }

        // ---- write Kc / Vc^T to LDS (C layout: row j = quad*4+r, col = l15) --
        if (w < 4) {
            int d = w * 16 + l15;
#pragma unroll
            for (int jt = 0; jt < 4; jt++)
#pragma unroll
                for (int r = 0; r < 4; r++)
                    sKc[(jt * 16 + quad * 4 + r) * 72 + d] = f2bf(pacc[jt][r]);
        } else {
            int d = (w - 4) * 16 + l15;
#pragma unroll
            for (int jt = 0; jt < 4; jt++) {
                ushortv4 p;
#pragma unroll
                for (int r = 0; r < 4; r++) p[r] = f2bf(pacc[jt][r]);
                *(ushortv4*)&sVt[d * 72 + jt * 16 + quad * 4] = p;
            }
        }
        __syncthreads();                    // B2: Kc/Vt visible; ALL proj sKV reads done

        // ---- issue next chunk's staging: hides under S+exp+PV ----
        if (ch < 7) STAGE_KV(ch + 1);

        // ---- S = Q * Kc^T (16 x 64), then P = exp(S) (no max needed) ----
#pragma unroll
        for (int jt = 0; jt < 4; jt++) {
            const ushort_t* kp = &sKc[(jt * 16 + l15) * 72 + quad * 8];
            short8 bk0 = *(const short8*)kp;
            short8 bk1 = *(const short8*)(kp + 32);
            floatx4 a = (floatx4){0.f, 0.f, 0.f, 0.f};
            a = __builtin_amdgcn_mfma_f32_16x16x32_bf16(aq0, bk0, a, 0, 0, 0);
            a = __builtin_amdgcn_mfma_f32_16x16x32_bf16(aq1, bk1, a, 0, 0, 0);
            ushortv4 pk;
#pragma unroll
            for (int r = 0; r < 4; r++) {
                float p = __expf(a[r]);
                lsum[r] += p;
                pk[r] = f2bf(p);
            }
#pragma unroll
            for (int r = 0; r < 4; r++)
                sp[(quad * 4 + r) * 72 + jt * 16 + l15] = pk[r];
        }

        // ---- O += P * V  (K = 64 j), per-wave private sp: no barrier ----
#pragma unroll
        for (int kk = 0; kk < 2; kk++) {
            short8 ap = *(const short8*)&sp[l15 * 72 + kk * 32 + quad * 8];
#pragma unroll
            for (int dt = 0; dt < 4; dt++) {
                short8 bv = *(const short8*)&sVt[(dt * 16 + l15) * 72 + kk * 32 + quad * 8];
                acc_o[dt] = __builtin_amdgcn_mfma_f32_16x16x32_bf16(ap, bv, acc_o[dt], 0, 0, 0);
            }
        }
    }

    // ---- final row-sum reduction (within 16-lane l15 groups) + write ----
#pragma unroll
    for (int r = 0; r < 4; r++) {
        float s = lsum[r];
#pragma unroll
        for (int off = 1; off < 16; off <<= 1) s += __shfl_xor(s, off);
        float inv = 1.0f / s;
        size_t rowo = (size_t)(b * 128 + w * 16 + quad * 4 + r) * 1024 + h * 64;
#pragma unroll
        for (int dt = 0; dt < 4; dt++)
            O[rowo + dt * 16 + l15] = f2bf(acc_o[dt][r] * inv);
    }
#undef STAGE_KV
}

// ---------------- launch ----------------
extern "C" void kernel_launch(void* const* d_in, const int* in_sizes, int n_in,
                              void* d_out, int out_size, void* d_ws, size_t ws_size,
                              hipStream_t stream) {
    const float* q   = (const float*)d_in[0];   // (64,128,512)
    const float* kv  = (const float*)d_in[1];   // (64,512,256)
    const float* Wq  = (const float*)d_in[2];   // (512,1024)
    const float* Wkv = (const float*)d_in[3];   // (256,2048)
    const float* Wo  = (const float*)d_in[4];   // (1024,512)
    const float* bo  = (const float*)d_in[5];   // (512,)
    float* out = (float*)d_out;

    char* ws = (char*)d_ws;
    ushort_t* qA    = (ushort_t*)(ws + 0);          //  8 MB  (8192 x 512)
    ushort_t* kvA   = (ushort_t*)(ws + 8388608);    // 16 MB  (32768 x 256)
    ushort_t* WqT   = (ushort_t*)(ws + 25165824);   //  1 MB  (1024 x 512)
    ushort_t* WkvT  = (ushort_t*)(ws + 26214400);   //  1 MB  (2048 x 256)
    ushort_t* WoT   = (ushort_t*)(ws + 27262976);   //  1 MB  (512 x 1024)
    ushort_t* attnO = (ushort_t*)(ws + 45088768);   // 16 MB  (8192 x 1024)

    // fused prep: 8-wide casts + tiled weight transposes, one launch
    hipLaunchKernelGGL(prep_kernel, dim3(6528), dim3(256), 0, stream,
                       q, kv, Wq, Wkv, Wo, qA, kvA, WqT, WkvT, WoT);

    // fused q-proj + kv-proj + attention (v10 structure + packed bf16 cvt)
    hipLaunchKernelGGL(fattn_kernel, dim3(1024), dim3(512), 0, stream,
                       qA, WqT, kvA, WkvT, attnO);

    // out = attnO @ Wo + bo  -- 64x64 tiles, 1024 blocks = 4 blocks/CU
    hipLaunchKernelGGL(gemm_bt_kernel, dim3(1024), dim3(256), 0, stream,
                       attnO, WoT, 8192, 512, 1024, out, bo);
}